// Round 10
// baseline (175.919 us; speedup 1.0000x reference)
//
#include <hip/hip_runtime.h>
#include <stdint.h>

// Radius-graph edge list, B=4, N=2048, cutoff 5.0.
// Output [2, B*P] int32: compacted valid edges (ascending flat index), -1 pad.
//
// Round-15: CELL LIST instead of brute force. r9 proved p-space brute force
// is VALU-bound at 10-40+ us (8.4M pair tests x >=12 VALU); only ~12K pairs
// are edges. A cell grid (size 10 >= cutoff) finds them with ~1.3M tests.
//   K1 fill_find (512 blk x 1024 thr):
//     blocks 0-3   = one WORKER per batch: bin 2048 pts into a 17^3 LDS-counted
//                    grid, LDS scan -> counting-sort (sorted-by-cell point
//                    list, all in LDS), then neighbor search: candidates from
//                    the 27-cell neighborhood; lanes process cell-sorted
//                    points so candidate loads broadcast. Edges -> LDS
//                    cbcnt[1024] (batch-local count-blocks of 2048 pairs;
//                    batch boundaries never shared -> worker exclusively owns
//                    counts[b*1024..+1024], no zeroing/atomic races) + global
//                    stash. All barriers intra-block.
//     blocks 4-511 = grid-stride -1 int4 fill of the whole 67 MB output.
//     Worker ~5 us hides under the ~12 us fill write stream.
//   K2 scatter (4096 blk x 256): own count, early-exit (4090/4096); prefix
//     from 16 KB counts; within-block order restored by O(cnt^2) rank on
//     pf (exact, pf unique); cnt > kCap -> exact brute-force ballot
//     recompute of that 2048-pair range (correctness independent of stash).
// Lessons pinned: r3 grid.sync=286us; r5 fence+nontemporal=233us (kernel
// boundary is the only cheap device fence); r6 barrier-after-big-stores =
// vmcnt(0) drain trap (workers store nothing big before their barriers);
// r8 same-line global atomics ~+10us (all hot atomics are LDS here).

namespace {
constexpr int kB = 4;
constexpr int kN = 2048;
constexpr int kP = kN * (kN - 1) / 2;              // 2096128
constexpr long long kTotal = (long long)kB * kP;   // 8384512
constexpr float kCut2 = 25.0f;                     // 5.0^2
constexpr int kCap = 64;                           // stash slots per count-blk
constexpr int kCBlkPerB = 1024;                    // count-blocks per batch
constexpr int kNCBlk = kB * kCBlkPerB;             // 4096 count-blocks
constexpr int kGrid1 = 512;                        // 4 workers + 508 fillers
constexpr int kThr1 = 1024;
constexpr int kFillN4 = (int)(2 * kTotal / 4);     // 4192256 int4s
constexpr int kCells = 17 * 17 * 17;               // 4913 (cell size 10, +-80)
}  // namespace

// p in [0,P) -> (i,j), i<j, triu row-major (fallback path only).
__device__ __forceinline__ void decode_pair(int p, int& i, int& j) {
  float t = sqrtf((float)(16769025 - 8 * p));
  int ii = (int)((4095.0f - t) * 0.5f);
  ii = ii < 0 ? 0 : (ii > kN - 2 ? kN - 2 : ii);
  while (ii > 0 && (ii * (4095 - ii)) / 2 > p) --ii;
  while (ii < kN - 2 && ((ii + 1) * (4094 - ii)) / 2 <= p) ++ii;
  i = ii;
  j = ii + 1 + (p - (ii * (4095 - ii)) / 2);
}

__device__ __forceinline__ bool pair_test(const float* __restrict__ x, int b, int p,
                                          int& gi, int& gj) {
  int i, j;
  decode_pair(p, i, j);
  const float* xb = x + (size_t)b * kN * 3;
  float dx = xb[3 * i + 0] - xb[3 * j + 0];
  float dy = xb[3 * i + 1] - xb[3 * j + 1];
  float dz = xb[3 * i + 2] - xb[3 * j + 2];
  gi = b * kN + i;
  gj = b * kN + j;
  return dx * dx + dy * dy + dz * dz <= kCut2;
}

__device__ __forceinline__ int cell_of(float X, float Y, float Z) {
  // cell size 10, clamp to [0,16] per dim. Clamping only merges far cells
  // into the boundary cell (adds candidates, never loses a true pair);
  // |dx|<=5 -> per-dim cell diff <=1 even with float rounding at boundaries.
  int cx = (int)floorf(X * 0.1f) + 8;
  int cy = (int)floorf(Y * 0.1f) + 8;
  int cz = (int)floorf(Z * 0.1f) + 8;
  cx = cx < 0 ? 0 : (cx > 16 ? 16 : cx);
  cy = cy < 0 ? 0 : (cy > 16 ? 16 : cy);
  cz = cz < 0 ? 0 : (cz > 16 ? 16 : cz);
  return (cx * 17 + cy) * 17 + cz;
}

// ---------------------------------------------------------------------------
// K1: blocks 0-3 = per-batch cell-list edge finder; blocks 4+ = -1 fill.
// ---------------------------------------------------------------------------
__global__ __launch_bounds__(kThr1) void fill_find_kernel(
    const float* __restrict__ x, uint32_t* __restrict__ counts,
    int2* __restrict__ stash, int* __restrict__ out) {
  const int t = threadIdx.x;
  const int bid = blockIdx.x;

  __shared__ uint32_t cnt[kCells];     // counts -> place-cursor -> end
  __shared__ uint16_t cstart[kCells];  // cell start in sorted[]
  __shared__ uint16_t sorted[kN];      // point indices, cell-sorted
  __shared__ uint32_t cbcnt[kCBlkPerB];
  __shared__ uint32_t wsum[16];

  if (bid >= 4) {
    // Filler: grid-stride -1 over the whole [2, B*P] int32 output.
    const int4 m1 = make_int4(-1, -1, -1, -1);
    int4* o = (int4*)out;
    for (uint32_t idx = (uint32_t)(bid - 4) * kThr1 + t; idx < (uint32_t)kFillN4;
         idx += (uint32_t)(kGrid1 - 4) * kThr1)
      o[idx] = m1;
    return;
  }

  // ---- Worker: batch b = bid ----
  const int b = bid;
  const float3* __restrict__ xb3 = (const float3*)(x + (size_t)b * kN * 3);
  const int lane = t & 63, wave = t >> 6;

  for (int c = t; c < kCells; c += kThr1) cnt[c] = 0;
  cbcnt[t] = 0;
  __syncthreads();

  // Bin pass A: count points per cell (LDS atomics).
  {
    float3 p0 = xb3[t];
    float3 p1 = xb3[t + kThr1];
    atomicAdd(&cnt[cell_of(p0.x, p0.y, p0.z)], 1u);
    atomicAdd(&cnt[cell_of(p1.x, p1.y, p1.z)], 1u);
  }
  __syncthreads();

  // Exclusive scan of 4913 cell counts (5 cells/thread).
  {
    uint32_t lc[5];
    uint32_t ssum = 0;
    const int c0 = t * 5;
#pragma unroll
    for (int q = 0; q < 5; ++q) {
      int c = c0 + q;
      lc[q] = (c < kCells) ? cnt[c] : 0u;
      ssum += lc[q];
    }
    uint32_t run = ssum;  // inclusive wave scan
    for (int o = 1; o < 64; o <<= 1) {
      uint32_t u = __shfl_up(run, o, 64);
      if (lane >= o) run += u;
    }
    if (lane == 63) wsum[wave] = run;
    __syncthreads();
    if (t == 0) {
      uint32_t acc = 0;
      for (int w = 0; w < 16; ++w) {
        uint32_t v = wsum[w];
        wsum[w] = acc;
        acc += v;
      }
    }
    __syncthreads();
    uint32_t excl = wsum[wave] + run - ssum;
#pragma unroll
    for (int q = 0; q < 5; ++q) {
      int c = c0 + q;
      if (c < kCells) {
        cstart[c] = (uint16_t)excl;  // begin
        cnt[c] = excl;               // cursor for place pass
        excl += lc[q];
      }
    }
  }
  __syncthreads();

  // Bin pass B: counting-sort point indices by cell.
  {
    float3 p0 = xb3[t];
    float3 p1 = xb3[t + kThr1];
    uint32_t s0 = atomicAdd(&cnt[cell_of(p0.x, p0.y, p0.z)], 1u);
    sorted[s0] = (uint16_t)t;
    uint32_t s1 = atomicAdd(&cnt[cell_of(p1.x, p1.y, p1.z)], 1u);
    sorted[s1] = (uint16_t)(t + kThr1);
  }
  __syncthreads();  // cnt[c] is now end-offset of cell c

  // Find: lanes walk the cell-sorted list -> 27-neighborhood candidate loads
  // are shared across adjacent lanes (broadcast from L1/LDS).
  for (int k = t; k < kN; k += kThr1) {
    const int q = sorted[k];
    const float3 pq = xb3[q];
    int cx = (int)floorf(pq.x * 0.1f) + 8;
    int cy = (int)floorf(pq.y * 0.1f) + 8;
    int cz = (int)floorf(pq.z * 0.1f) + 8;
    cx = cx < 0 ? 0 : (cx > 16 ? 16 : cx);
    cy = cy < 0 ? 0 : (cy > 16 ? 16 : cy);
    cz = cz < 0 ? 0 : (cz > 16 ? 16 : cz);
    const int x0 = cx > 0 ? cx - 1 : 0, x1 = cx < 16 ? cx + 1 : 16;
    const int y0 = cy > 0 ? cy - 1 : 0, y1 = cy < 16 ? cy + 1 : 16;
    const int z0 = cz > 0 ? cz - 1 : 0, z1 = cz < 16 ? cz + 1 : 16;
    const int gi = (b << 11) + q;
    for (int ax = x0; ax <= x1; ++ax)
      for (int ay = y0; ay <= y1; ++ay) {
        const int rowc = (ax * 17 + ay) * 17;
        for (int az = z0; az <= z1; ++az) {
          const int nc = rowc + az;
          const uint32_t sE = cnt[nc];
          for (uint32_t s = cstart[nc]; s < sE; ++s) {
            const int r = sorted[s];
            if (r <= q) continue;
            const float3 pr = xb3[r];
            const float dx = pq.x - pr.x, dy = pq.y - pr.y, dz = pq.z - pr.z;
            if (dx * dx + dy * dy + dz * dz <= kCut2) {
              const int pf = (q * (4095 - q)) / 2 + (r - q - 1);
              const int blk = pf >> 11;
              const uint32_t slot = atomicAdd(&cbcnt[blk], 1u);
              if (slot < (uint32_t)kCap)
                stash[(size_t)((b << 10) + blk) * kCap + slot] =
                    make_int2(gi, (b << 11) + r);
            }
          }
        }
      }
  }
  __syncthreads();
  counts[(b << 10) + t] = cbcnt[t];  // sole owner of this 1024-range
}

// ---------------------------------------------------------------------------
// K2: scatter. Early-exit for empty blocks; pf-rank restores within-block
// order; exact brute-force fallback if cnt > kCap.
// ---------------------------------------------------------------------------
__global__ __launch_bounds__(256) void scatter_kernel(
    const float* __restrict__ x, const uint32_t* __restrict__ counts,
    const int2* __restrict__ stash, int* __restrict__ out) {
  const int bid = blockIdx.x;
  const int t = threadIdx.x;

  const uint32_t cnt = counts[bid];
  if (cnt == 0) return;  // ~4090/4096 blocks

  // Self-service prefix: offset = sum(counts[idx < bid]) from 16 KB L2-hot.
  const uint4* c4 = (const uint4*)counts;  // exactly 4096 entries
  uint32_t part = 0;
#pragma unroll
  for (int q = 0; q < 4; ++q) {
    uint4 v = c4[t * 4 + q];
    int i0 = t * 16 + q * 4;
    part += (i0 + 0 < bid) ? v.x : 0u;
    part += (i0 + 1 < bid) ? v.y : 0u;
    part += (i0 + 2 < bid) ? v.z : 0u;
    part += (i0 + 3 < bid) ? v.w : 0u;
  }
  for (int o = 32; o > 0; o >>= 1) part += __shfl_down(part, o, 64);
  __shared__ uint32_t wred[4];
  if ((t & 63) == 0) wred[t >> 6] = part;
  __syncthreads();
  if (t == 0) wred[0] = wred[0] + wred[1] + wred[2] + wred[3];
  __syncthreads();
  const uint32_t off = wred[0];

  if (cnt <= (uint32_t)kCap) {
    __shared__ int2 ebuf[kCap];
    __shared__ uint32_t pfb[kCap];
    for (uint32_t e = t; e < cnt; e += 256) {
      int2 v = stash[(size_t)bid * kCap + e];
      ebuf[e] = v;
      int i = v.x & 2047, j = v.y & 2047;
      pfb[e] = (uint32_t)((i * (4095 - i)) / 2 + (j - i - 1));
    }
    __syncthreads();
    for (uint32_t e = t; e < cnt; e += 256) {
      uint32_t mypf = pfb[e];
      uint32_t rank = 0;
      for (uint32_t f = 0; f < cnt; ++f) rank += (pfb[f] < mypf) ? 1u : 0u;
      out[off + rank] = ebuf[e].x;
      out[(size_t)kTotal + off + rank] = ebuf[e].y;
    }
    return;
  }

  // Fallback (cnt > kCap): exact ballot recompute of this batch-local
  // 2048-pair range; counts match K1's exact count by construction.
  const int wave = t >> 6, lane = t & 63;
  const int b = bid >> 10;
  const int p0 = (bid & 1023) << 11;
  __shared__ uint32_t slot[32];
  unsigned long long masks[8];
  int gi[8], gj[8];
  bool fl[8];
#pragma unroll
  for (int k = 0; k < 8; ++k) {
    int p = p0 + k * 256 + t;
    fl[k] = (p < kP) && pair_test(x, b, p, gi[k], gj[k]);
    masks[k] = __ballot(fl[k]);
    if (lane == 0) slot[k * 4 + wave] = (uint32_t)__popcll(masks[k]);
  }
  __syncthreads();
  if (t == 0) {
    uint32_t run = 0;
    for (int s = 0; s < 32; ++s) {
      uint32_t c = slot[s];
      slot[s] = run;
      run += c;
    }
  }
  __syncthreads();
#pragma unroll
  for (int k = 0; k < 8; ++k) {
    if (fl[k]) {
      uint32_t pos = off + slot[k * 4 + wave] +
                     (uint32_t)__popcll(masks[k] & ((1ULL << lane) - 1ULL));
      out[pos] = gi[k];
      out[(size_t)kTotal + pos] = gj[k];
    }
  }
}

extern "C" void kernel_launch(void* const* d_in, const int* in_sizes, int n_in,
                              void* d_out, int out_size, void* d_ws, size_t ws_size,
                              hipStream_t stream) {
  const float* x = (const float*)d_in[0];
  int* out = (int*)d_out;
  uint32_t* counts = (uint32_t*)d_ws;           // [4096]
  int2* stash = (int2*)(counts + 4096);         // [4096 * 64] = 2 MB

  hipLaunchKernelGGL(fill_find_kernel, dim3(kGrid1), dim3(kThr1), 0, stream, x,
                     counts, stash, out);
  hipLaunchKernelGGL(scatter_kernel, dim3(kNCBlk), dim3(256), 0, stream, x, counts,
                     stash, out);
}